// Round 1
// baseline (348.485 us; speedup 1.0000x reference)
//
#include <hip/hip_runtime.h>

typedef unsigned short u16;
typedef short short8 __attribute__((ext_vector_type(8)));
typedef float f32x4 __attribute__((ext_vector_type(4)));
typedef unsigned short u16x4 __attribute__((ext_vector_type(4)));

#define MFMA16(a, b, c) __builtin_amdgcn_mfma_f32_16x16x32_bf16((a), (b), (c), 0, 0, 0)

__device__ __forceinline__ u16 f2bf(float f) {
    unsigned u = __builtin_bit_cast(unsigned, f);
    u += 0x7FFFu + ((u >> 16) & 1u);   // RNE
    return (u16)(u >> 16);
}

__device__ __forceinline__ void async16(void* lds, const void* g) {
    __builtin_amdgcn_global_load_lds(
        (const __attribute__((address_space(1))) void*)g,
        (__attribute__((address_space(3))) void*)lds, 16, 0, 0);
}

// ---------------- cast fp32 -> bf16 (optionally scaling first scaleCut elems by 0.125) ----
__global__ __launch_bounds__(256) void castk(const float* __restrict__ in,
                                             u16* __restrict__ out, int n, int scaleCut) {
    int i = (blockIdx.x * 256 + threadIdx.x) * 4;
    if (i >= n) return;
    float4 v = *(const float4*)(in + i);
    float sc = (i < scaleCut) ? 0.125f : 1.0f;
    u16x4 r;
    r[0] = f2bf(v.x * sc); r[1] = f2bf(v.y * sc);
    r[2] = f2bf(v.z * sc); r[3] = f2bf(v.w * sc);
    *(u16x4*)(out + i) = r;
}

// ---------------- GEMM: C[M,N] = A[M,K] * B[N,K]^T  (all bf16 in, m97 structure) --------
template <bool OUT_BF16>
__global__ __launch_bounds__(256, 2) void gemm_bt(const u16* __restrict__ A,
                                                  const u16* __restrict__ B,
                                                  void* __restrict__ Cv,
                                                  const float* __restrict__ bias,
                                                  int M, int N, int K) {
    __shared__ u16 As[128 * 32];
    __shared__ u16 Bs[128 * 32];
    const int tid = threadIdx.x;
    const int w = tid >> 6, l = tid & 63;
    const int g = l >> 4, lo = l & 15;
    const int mtiles = M >> 7;
    const int tm = blockIdx.x % mtiles, tn = blockIdx.x / mtiles;
    const int rowBase = tm << 7, colBase = tn << 7;
    const int wrow = w >> 1, wcol = w & 1;

    f32x4 acc[4][4] = {};

    const int srow = l >> 2;          // row within 16-row segment
    const int scol = (l & 3) * 8;     // k-elem offset
    const int nk = K >> 5;
    for (int kt = 0; kt < nk; ++kt) {
        const int kbase = kt * 32 + scol;
#pragma unroll
        for (int it = 0; it < 2; ++it) {
            const int seg = it * 4 + w;            // 0..7
            const int r = seg * 16 + srow;         // 0..127
            async16(&As[seg * 512], &A[(size_t)(rowBase + r) * K + kbase]);
            async16(&Bs[seg * 512], &B[(size_t)(colBase + r) * K + kbase]);
        }
        __syncthreads();
        short8 af[4], bf[4];
#pragma unroll
        for (int mi = 0; mi < 4; ++mi)
            af[mi] = *(const short8*)&As[(wrow * 64 + mi * 16 + lo) * 32 + g * 8];
#pragma unroll
        for (int ni = 0; ni < 4; ++ni)
            bf[ni] = *(const short8*)&Bs[(wcol * 64 + ni * 16 + lo) * 32 + g * 8];
#pragma unroll
        for (int mi = 0; mi < 4; ++mi)
#pragma unroll
            for (int ni = 0; ni < 4; ++ni)
                acc[mi][ni] = MFMA16(af[mi], bf[ni], acc[mi][ni]);
        __syncthreads();
    }

#pragma unroll
    for (int ni = 0; ni < 4; ++ni) {
        const int c = colBase + wcol * 64 + ni * 16 + lo;
        float bv = 0.f;
        if constexpr (!OUT_BF16) bv = bias[c];
#pragma unroll
        for (int mi = 0; mi < 4; ++mi) {
            const int r0 = rowBase + wrow * 64 + mi * 16 + g * 4;
#pragma unroll
            for (int i = 0; i < 4; ++i) {
                float v = acc[mi][ni][i];
                if constexpr (OUT_BF16)
                    ((u16*)Cv)[(size_t)(r0 + i) * N + c] = f2bf(v);
                else
                    ((float*)Cv)[(size_t)(r0 + i) * N + c] = v + bv;
            }
        }
    }
}

// ---------------- flash attention: qkv bf16 [8192,3072] -> out bf16 [8192,1024] ---------
// grid (64 = B*H, 16 = N/128), block 256. Per wave: 32 q-rows. KV tile = 64.
__global__ __launch_bounds__(256, 2) void attn_fwd(const u16* __restrict__ qkv,
                                                   u16* __restrict__ outb) {
    __shared__ u16 Ks[64 * 64];        // swizzled [key][d]
    __shared__ u16 Vt[64 * 64];        // swizzled transposed [d][key]
    __shared__ u16 Ps[4][32 * 64];     // per-wave P, swizzled [row][key]
    const int tid = threadIdx.x;
    const int w = tid >> 6, l = tid & 63;
    const int g = l >> 4, lo = l & 15;
    const int bh = blockIdx.x;
    const int b = bh >> 4, h = bh & 15;
    const int qt = blockIdx.y;
    const size_t rowQ0 = (size_t)b * 2048 + qt * 128 + w * 32;

    // Q fragments, held in registers for the whole kernel (scale folded into w_q)
    short8 qf[2][2];
#pragma unroll
    for (int m = 0; m < 2; ++m) {
        const u16* qp = qkv + (rowQ0 + m * 16 + lo) * 3072 + h * 64;
        qf[m][0] = *(const short8*)(qp + g * 8);
        qf[m][1] = *(const short8*)(qp + 32 + g * 8);
    }

    f32x4 o[2][4] = {};
    float mrow[2][4], lrow[2][4];
#pragma unroll
    for (int m = 0; m < 2; ++m)
#pragma unroll
        for (int i = 0; i < 4; ++i) { mrow[m][i] = -1e30f; lrow[m][i] = 0.f; }

    const int vkey = tid & 63;
    const int vdimb = (tid >> 6) * 16;

    for (int kt = 0; kt < 32; ++kt) {
        const int krow0 = kt * 64;
        // ---- stage K tile via global_load_lds, pre-swizzled source (rule #21) ----
#pragma unroll
        for (int it = 0; it < 2; ++it) {
            const int Lb = w * 1024 + it * 4096 + l * 16;      // per-lane LDS byte
            const int key = Lb >> 7;
            const int srcb = Lb ^ ((key & 7) << 4);
            const int col = (srcb & 127) >> 1;
            async16((char*)Ks + (w * 1024 + it * 4096),
                    qkv + ((size_t)b * 2048 + krow0 + key) * 3072 + 1024 + h * 64 + col);
        }
        // ---- stage V transposed (reg-staged), swizzled writes ----
        {
            const u16* vp = qkv + ((size_t)b * 2048 + krow0 + vkey) * 3072 + 2048 + h * 64 + vdimb;
            short8 v0 = *(const short8*)(vp);
            short8 v1 = *(const short8*)(vp + 8);
#pragma unroll
            for (int i = 0; i < 8; ++i) {
                int d = vdimb + i;
                *(u16*)((char*)Vt + ((d * 128 + vkey * 2) ^ ((d & 7) << 4))) = (u16)v0[i];
            }
#pragma unroll
            for (int i = 0; i < 8; ++i) {
                int d = vdimb + 8 + i;
                *(u16*)((char*)Vt + ((d * 128 + vkey * 2) ^ ((d & 7) << 4))) = (u16)v1[i];
            }
        }
        __syncthreads();

        // ---- S = Q K^T ----
        short8 kb[4][2];
#pragma unroll
        for (int nt = 0; nt < 4; ++nt) {
            const int key = nt * 16 + lo;
            const int sw = (key & 7) << 4;
            kb[nt][0] = *(const short8*)((const char*)Ks + ((key * 128 + g * 16) ^ sw));
            kb[nt][1] = *(const short8*)((const char*)Ks + ((key * 128 + 64 + g * 16) ^ sw));
        }
        f32x4 s[2][4];
#pragma unroll
        for (int m = 0; m < 2; ++m)
#pragma unroll
            for (int nt = 0; nt < 4; ++nt) {
                f32x4 z = {0.f, 0.f, 0.f, 0.f};
                z = MFMA16(qf[m][0], kb[nt][0], z);
                s[m][nt] = MFMA16(qf[m][1], kb[nt][1], z);
            }

        // ---- online softmax ----
#pragma unroll
        for (int m = 0; m < 2; ++m) {
            float al[4], ps[4];
#pragma unroll
            for (int i = 0; i < 4; ++i) {
                float v = fmaxf(fmaxf(s[m][0][i], s[m][1][i]), fmaxf(s[m][2][i], s[m][3][i]));
                v = fmaxf(v, __shfl_xor(v, 1));
                v = fmaxf(v, __shfl_xor(v, 2));
                v = fmaxf(v, __shfl_xor(v, 4));
                v = fmaxf(v, __shfl_xor(v, 8));
                float nm = fmaxf(mrow[m][i], v);
                al[i] = __expf(mrow[m][i] - nm);
                mrow[m][i] = nm;
                ps[i] = 0.f;
            }
#pragma unroll
            for (int nt = 0; nt < 4; ++nt)
#pragma unroll
                for (int i = 0; i < 4; ++i) {
                    float p = __expf(s[m][nt][i] - mrow[m][i]);
                    s[m][nt][i] = p;
                    ps[i] += p;
                }
#pragma unroll
            for (int i = 0; i < 4; ++i) {
                float t = ps[i];
                t += __shfl_xor(t, 1); t += __shfl_xor(t, 2);
                t += __shfl_xor(t, 4); t += __shfl_xor(t, 8);
                lrow[m][i] = lrow[m][i] * al[i] + t;
#pragma unroll
                for (int dt = 0; dt < 4; ++dt) o[m][dt][i] *= al[i];
            }
            // write P (bf16) to per-wave swizzled LDS
#pragma unroll
            for (int nt = 0; nt < 4; ++nt)
#pragma unroll
                for (int i = 0; i < 4; ++i) {
                    int row = m * 16 + g * 4 + i;
                    int key = nt * 16 + lo;
                    *(u16*)((char*)Ps[w] + ((row * 128 + key * 2) ^ ((row & 7) << 4))) =
                        f2bf(s[m][nt][i]);
                }
        }

        // ---- O += P V ----
        short8 pa[2][2], vb[2][4];
#pragma unroll
        for (int m = 0; m < 2; ++m) {
            int row = m * 16 + lo;
            int sw = (row & 7) << 4;
            pa[m][0] = *(const short8*)((const char*)Ps[w] + ((row * 128 + g * 16) ^ sw));
            pa[m][1] = *(const short8*)((const char*)Ps[w] + ((row * 128 + 64 + g * 16) ^ sw));
        }
#pragma unroll
        for (int kc = 0; kc < 2; ++kc)
#pragma unroll
            for (int dt = 0; dt < 4; ++dt) {
                int d = dt * 16 + lo;
                vb[kc][dt] = *(const short8*)((const char*)Vt +
                                ((d * 128 + kc * 64 + g * 16) ^ ((d & 7) << 4)));
            }
#pragma unroll
        for (int m = 0; m < 2; ++m)
#pragma unroll
            for (int dt = 0; dt < 4; ++dt) {
                o[m][dt] = MFMA16(pa[m][0], vb[0][dt], o[m][dt]);
                o[m][dt] = MFMA16(pa[m][1], vb[1][dt], o[m][dt]);
            }
        __syncthreads();
    }

    // ---- epilogue: normalize and store bf16 [8192,1024] ----
#pragma unroll
    for (int m = 0; m < 2; ++m) {
        float rl[4];
#pragma unroll
        for (int i = 0; i < 4; ++i) rl[i] = 1.f / lrow[m][i];
#pragma unroll
        for (int dt = 0; dt < 4; ++dt)
#pragma unroll
            for (int i = 0; i < 4; ++i) {
                size_t r = rowQ0 + m * 16 + g * 4 + i;
                int c = h * 64 + dt * 16 + lo;
                outb[r * 1024 + c] = f2bf(o[m][dt][i] * rl[i]);
            }
    }
}

// ---------------- launch ----------------------------------------------------------------
extern "C" void kernel_launch(void* const* d_in, const int* in_sizes, int n_in,
                              void* d_out, int out_size, void* d_ws, size_t ws_size,
                              hipStream_t stream) {
    const float* x     = (const float*)d_in[0];   // [4,2048,1024]
    const float* w_qkv = (const float*)d_in[1];   // [3072,1024]
    const float* w_out = (const float*)d_in[2];   // [1024,1024]
    const float* b_out = (const float*)d_in[3];   // [1024]
    float* out = (float*)d_out;                   // [4,2048,1024] fp32

    u16* xb    = (u16*)d_ws;                              //  8192*1024
    u16* wqkvb = xb    + (size_t)8192 * 1024;             //  3072*1024
    u16* woutb = wqkvb + (size_t)3072 * 1024;             //  1024*1024
    u16* qkvb  = woutb + (size_t)1024 * 1024;             //  8192*3072
    u16* attb  = qkvb  + (size_t)8192 * 3072;             //  8192*1024
    // total ws use: 92,274,688 bytes

    castk<<<8192, 256, 0, stream>>>(x, xb, 8192 * 1024, 0);
    castk<<<3072, 256, 0, stream>>>(w_qkv, wqkvb, 3072 * 1024, 1024 * 1024); // scale q rows by 0.125
    castk<<<1024, 256, 0, stream>>>(w_out, woutb, 1024 * 1024, 0);

    gemm_bt<true><<<dim3((8192 / 128) * (3072 / 128)), 256, 0, stream>>>(
        xb, wqkvb, qkvb, nullptr, 8192, 3072, 1024);

    attn_fwd<<<dim3(64, 16), 256, 0, stream>>>(qkvb, attb);

    gemm_bt<false><<<dim3((8192 / 128) * (1024 / 128)), 256, 0, stream>>>(
        attb, woutb, out, b_out, 8192, 1024, 1024);
}

// Round 2
// 197.989 us; speedup vs baseline: 1.7601x; 1.7601x over previous
//
#include <hip/hip_runtime.h>

typedef unsigned short u16;
typedef short short8 __attribute__((ext_vector_type(8)));
typedef float f32x4 __attribute__((ext_vector_type(4)));
typedef float f32x16 __attribute__((ext_vector_type(16)));
typedef unsigned short u16x4 __attribute__((ext_vector_type(4)));
typedef unsigned int u32x4 __attribute__((ext_vector_type(4)));

#define MFMA16(a, b, c) __builtin_amdgcn_mfma_f32_16x16x32_bf16((a), (b), (c), 0, 0, 0)
#define MFMA32(a, b, c) __builtin_amdgcn_mfma_f32_32x32x16_bf16((a), (b), (c), 0, 0, 0)

#if __has_builtin(__builtin_amdgcn_exp2f)
#define EXP2F(x) __builtin_amdgcn_exp2f(x)
#else
#define EXP2F(x) exp2f(x)
#endif

__device__ __forceinline__ u16 f2bf(float f) {
    unsigned u = __builtin_bit_cast(unsigned, f);
    u += 0x7FFFu + ((u >> 16) & 1u);   // RNE
    return (u16)(u >> 16);
}

__device__ __forceinline__ void async16(void* lds, const void* g) {
    __builtin_amdgcn_global_load_lds(
        (const __attribute__((address_space(1))) void*)g,
        (__attribute__((address_space(3))) void*)lds, 16, 0, 0);
}

__device__ __forceinline__ unsigned cvtpk(float lo, float hi) {
    unsigned r;
    asm("v_cvt_pk_bf16_f32 %0, %1, %2" : "=v"(r) : "v"(lo), "v"(hi));
    return r;
}
__device__ __forceinline__ void plswap(unsigned& a, unsigned& b) {
    asm("v_permlane32_swap_b32 %0, %1" : "+v"(a), "+v"(b));
}

// pack one S^T tile (16 f32, keys crow(r,hi)) into two A-fragments (ksl=0,1)
__device__ __forceinline__ void packP(const f32x16& s, short8& f0, short8& f1) {
    u32x4 u0, u1;
    {
        unsigned a = cvtpk(s[0], s[1]), b = cvtpk(s[4], s[5]);
        plswap(a, b);
        unsigned c = cvtpk(s[2], s[3]), d = cvtpk(s[6], s[7]);
        plswap(c, d);
        u0[0] = a; u0[1] = c; u0[2] = b; u0[3] = d;
    }
    {
        unsigned a = cvtpk(s[8], s[9]), b = cvtpk(s[12], s[13]);
        plswap(a, b);
        unsigned c = cvtpk(s[10], s[11]), d = cvtpk(s[14], s[15]);
        plswap(c, d);
        u1[0] = a; u1[1] = c; u1[2] = b; u1[3] = d;
    }
    f0 = __builtin_bit_cast(short8, u0);
    f1 = __builtin_bit_cast(short8, u1);
}

// ---------------- cast fp32 -> bf16 (first scaleCut elems scaled by 0.125*log2e) ---------
__global__ __launch_bounds__(256) void castk(const float* __restrict__ in,
                                             u16* __restrict__ out, int n, int scaleCut) {
    int i = (blockIdx.x * 256 + threadIdx.x) * 4;
    if (i >= n) return;
    float4 v = *(const float4*)(in + i);
    float sc = (i < scaleCut) ? 0.18033688011112042f : 1.0f;  // 0.125 * log2(e)
    u16x4 r;
    r[0] = f2bf(v.x * sc); r[1] = f2bf(v.y * sc);
    r[2] = f2bf(v.z * sc); r[3] = f2bf(v.w * sc);
    *(u16x4*)(out + i) = r;
}

// ---------------- GEMM: C = A[M,K] * B[N,K]^T  (bf16 in, m97 structure) ------------------
// MODE 0: split epilogue -> qkb (cols<2048, ld 2048, bf16) / vtg transposed [bh][d][2048]
// MODE 1: fp32 + bias epilogue
template <int MODE>
__global__ __launch_bounds__(256, 2) void gemm_bt(const u16* __restrict__ A,
                                                  const u16* __restrict__ B,
                                                  void* __restrict__ C0,
                                                  void* __restrict__ C1,
                                                  int M, int N, int K) {
    __shared__ u16 As[128 * 32];
    __shared__ u16 Bs[128 * 32];
    const int tid = threadIdx.x;
    const int w = tid >> 6, l = tid & 63;
    const int g = l >> 4, lo = l & 15;
    const int mtiles = M >> 7;
    const int tm = blockIdx.x % mtiles, tn = blockIdx.x / mtiles;
    const int rowBase = tm << 7, colBase = tn << 7;
    const int wrow = w >> 1, wcol = w & 1;

    f32x4 acc[4][4] = {};

    const int srow = l >> 2;
    const int scol = (l & 3) * 8;
    const int nk = K >> 5;
    for (int kt = 0; kt < nk; ++kt) {
        const int kbase = kt * 32 + scol;
#pragma unroll
        for (int it = 0; it < 2; ++it) {
            const int seg = it * 4 + w;
            const int r = seg * 16 + srow;
            async16(&As[seg * 512], &A[(size_t)(rowBase + r) * K + kbase]);
            async16(&Bs[seg * 512], &B[(size_t)(colBase + r) * K + kbase]);
        }
        __syncthreads();
        short8 af[4], bf[4];
#pragma unroll
        for (int mi = 0; mi < 4; ++mi)
            af[mi] = *(const short8*)&As[(wrow * 64 + mi * 16 + lo) * 32 + g * 8];
#pragma unroll
        for (int ni = 0; ni < 4; ++ni)
            bf[ni] = *(const short8*)&Bs[(wcol * 64 + ni * 16 + lo) * 32 + g * 8];
#pragma unroll
        for (int mi = 0; mi < 4; ++mi)
#pragma unroll
            for (int ni = 0; ni < 4; ++ni)
                acc[mi][ni] = MFMA16(af[mi], bf[ni], acc[mi][ni]);
        __syncthreads();
    }

    if constexpr (MODE == 0) {
        if (colBase < 2048) {   // Q/K region -> qkb, ld = 2048
            u16* qk = (u16*)C0;
#pragma unroll
            for (int ni = 0; ni < 4; ++ni) {
                const int c = colBase + wcol * 64 + ni * 16 + lo;
#pragma unroll
                for (int mi = 0; mi < 4; ++mi) {
                    const int r0 = rowBase + wrow * 64 + mi * 16 + g * 4;
#pragma unroll
                    for (int i = 0; i < 4; ++i)
                        qk[(size_t)(r0 + i) * 2048 + c] = f2bf(acc[mi][ni][i]);
                }
            }
        } else {                // V region -> vtg transposed [bh*64+d][2048]
            u16* vt = (u16*)C1;
            const int b = rowBase >> 11;
#pragma unroll
            for (int ni = 0; ni < 4; ++ni) {
                const int c = colBase + wcol * 64 + ni * 16 + lo;
                const int hh = (c - 2048) >> 6, d = (c - 2048) & 63;
                u16* vrow = vt + ((size_t)((b * 16 + hh) * 64 + d)) * 2048;
#pragma unroll
                for (int mi = 0; mi < 4; ++mi) {
                    const int r0 = rowBase + wrow * 64 + mi * 16 + g * 4;
                    u16x4 pk;
#pragma unroll
                    for (int i = 0; i < 4; ++i) pk[i] = f2bf(acc[mi][ni][i]);
                    *(u16x4*)(vrow + (r0 & 2047)) = pk;
                }
            }
        }
    } else {
        float* Cf = (float*)C0;
        const float* bias = (const float*)C1;
#pragma unroll
        for (int ni = 0; ni < 4; ++ni) {
            const int c = colBase + wcol * 64 + ni * 16 + lo;
            const float bv = bias[c];
#pragma unroll
            for (int mi = 0; mi < 4; ++mi) {
                const int r0 = rowBase + wrow * 64 + mi * 16 + g * 4;
#pragma unroll
                for (int i = 0; i < 4; ++i)
                    Cf[(size_t)(r0 + i) * N + c] = acc[mi][ni][i] + bv;
            }
        }
    }
}

// ---------------- flash attention, swapped-QK^T 32x32 structure --------------------------
// qkb [8192][2048] bf16 (Q cols 0..1023, K cols 1024..2047), vtg [64][64][2048] bf16.
// grid 1024 (XCD-swizzled -> bh, qtile), block 256 = 4 waves, 32 q-rows/wave, KVBLK 64.
__global__ __launch_bounds__(256, 3) void attn_fwd(const u16* __restrict__ qkb,
                                                   const u16* __restrict__ vtg,
                                                   u16* __restrict__ outb) {
    __shared__ u16 Ks[2][64 * 64];
    __shared__ u16 Vs[2][64 * 64];
    __shared__ float Abuf[4][32];
    const int tid = threadIdx.x;
    const int w = tid >> 6, l = tid & 63;
    const int hi = l >> 5, lq = l & 31;

    int lin = (blockIdx.x & 7) * 128 + (blockIdx.x >> 3);  // bijective XCD chunking
    const int bh = lin >> 4, qt = lin & 15;
    const int b = bh >> 4, h = bh & 15;
    const int q0 = qt * 128 + w * 32;
    const size_t rowQ = (size_t)b * 2048 + q0;

    // Q fragments (B-operand), scale+log2e already folded into w_qkv
    short8 qf[4];
#pragma unroll
    for (int ks = 0; ks < 4; ++ks)
        qf[ks] = *(const short8*)(qkb + (rowQ + lq) * 2048 + h * 64 + ks * 16 + hi * 8);

    // swizzled LDS byte offsets (same table serves K[t][ks] and Vt[dt][kstep])
    int koff[2][4];
#pragma unroll
    for (int t = 0; t < 2; ++t)
#pragma unroll
        for (int ks = 0; ks < 4; ++ks) {
            const int row = t * 32 + lq;
            koff[t][ks] = (row * 128 + ks * 32 + hi * 16) ^ ((row & 7) << 4);
        }

    // staging sources (pre-swizzled so linear global_load_lds dest yields swizzled layout)
    const int L0 = tid * 16, L1 = tid * 16 + 4096;
    const int kr0 = L0 >> 7, kc0 = ((L0 ^ ((kr0 & 7) << 4)) & 127) >> 1;
    const int kr1 = L1 >> 7, kc1 = ((L1 ^ ((kr1 & 7) << 4)) & 127) >> 1;
    const u16* ks0 = qkb + (size_t)(b * 2048 + kr0) * 2048 + 1024 + h * 64 + kc0;
    const u16* ks1 = qkb + (size_t)(b * 2048 + kr1) * 2048 + 1024 + h * 64 + kc1;
    const u16* vs0 = vtg + ((size_t)bh * 64 + kr0) * 2048 + kc0;
    const u16* vs1 = vtg + ((size_t)bh * 64 + kr1) * 2048 + kc1;
    const size_t KADV = (size_t)64 * 2048;

    f32x16 O0, O1;
#pragma unroll
    for (int i = 0; i < 16; ++i) { O0[i] = 0.f; O1[i] = 0.f; }
    float mrun = -1e30f, lsum = 0.f;

    // prologue: stage tile 0 into buffer 0
    async16((char*)Ks[0] + L0, ks0); async16((char*)Ks[0] + L1, ks1);
    async16((char*)Vs[0] + L0, vs0); async16((char*)Vs[0] + L1, vs1);
    ks0 += KADV; ks1 += KADV; vs0 += 64; vs1 += 64;

    int cur = 0;
    for (int kt = 0; kt < 32; ++kt) {
        __syncthreads();   // staged buf[cur] ready (each wave drains own vmcnt at barrier)
        if (kt < 31) {
            const int nx = cur ^ 1;
            async16((char*)Ks[nx] + L0, ks0); async16((char*)Ks[nx] + L1, ks1);
            async16((char*)Vs[nx] + L0, vs0); async16((char*)Vs[nx] + L1, vs1);
            ks0 += KADV; ks1 += KADV; vs0 += 64; vs1 += 64;
        }
        const char* kb = (const char*)Ks[cur];
        const char* vb = (const char*)Vs[cur];

        // ---- S^T = K Q^T : lane holds q = lq, keys crow(r,hi) (+32 for s1) ----
        f32x16 s0, s1;
#pragma unroll
        for (int i = 0; i < 16; ++i) { s0[i] = 0.f; s1[i] = 0.f; }
#pragma unroll
        for (int ks = 0; ks < 4; ++ks) {
            const short8 k0 = *(const short8*)(kb + koff[0][ks]);
            const short8 k1 = *(const short8*)(kb + koff[1][ks]);
            s0 = MFMA32(k0, qf[ks], s0);
            s1 = MFMA32(k1, qf[ks], s1);
        }

        // ---- in-register online softmax (log2 space) ----
        float pmax = s0[0];
#pragma unroll
        for (int i = 1; i < 16; ++i) pmax = fmaxf(pmax, s0[i]);
#pragma unroll
        for (int i = 0; i < 16; ++i) pmax = fmaxf(pmax, s1[i]);
        pmax = fmaxf(pmax, __shfl_xor(pmax, 32));

        if (!__all(pmax - mrun <= 10.f)) {      // defer-max: rare after tile 0
            const float mn = fmaxf(mrun, pmax);
            const float al = EXP2F(mrun - mn);
            mrun = mn;
            lsum *= al;
            Abuf[w][lq] = al;
#pragma unroll
            for (int r = 0; r < 16; ++r) {
                const float a2 = Abuf[w][(r & 3) + 8 * (r >> 2) + 4 * hi];
                O0[r] *= a2; O1[r] *= a2;
            }
        }
        float sum = 0.f;
#pragma unroll
        for (int i = 0; i < 16; ++i) { const float p = EXP2F(s0[i] - mrun); s0[i] = p; sum += p; }
#pragma unroll
        for (int i = 0; i < 16; ++i) { const float p = EXP2F(s1[i] - mrun); s1[i] = p; sum += p; }
        sum += __shfl_xor(sum, 32);
        lsum += sum;

        // ---- P -> A-fragments (cvt_pk + permlane32_swap, no LDS) ----
        short8 pf[2][2];
        packP(s0, pf[0][0], pf[0][1]);
        packP(s1, pf[1][0], pf[1][1]);

        // ---- O += P V ----
#pragma unroll
        for (int t = 0; t < 2; ++t)
#pragma unroll
            for (int ksl = 0; ksl < 2; ++ksl) {
                const int kstep = t * 2 + ksl;
                const short8 v0 = *(const short8*)(vb + koff[0][kstep]);
                const short8 v1 = *(const short8*)(vb + koff[1][kstep]);
                O0 = MFMA32(pf[t][ksl], v0, O0);
                O1 = MFMA32(pf[t][ksl], v1, O1);
            }
        cur ^= 1;
    }

    // ---- epilogue: normalize, store bf16 ----
    Abuf[w][lq] = 1.f / lsum;
#pragma unroll
    for (int r = 0; r < 16; ++r) {
        const int qrow = (r & 3) + 8 * (r >> 2) + 4 * hi;
        const float linv = Abuf[w][qrow];
        u16* op = outb + (rowQ + qrow) * 1024 + h * 64 + lq;
        op[0] = f2bf(O0[r] * linv);
        op[32] = f2bf(O1[r] * linv);
    }
}

// ---------------- launch ----------------------------------------------------------------
extern "C" void kernel_launch(void* const* d_in, const int* in_sizes, int n_in,
                              void* d_out, int out_size, void* d_ws, size_t ws_size,
                              hipStream_t stream) {
    const float* x     = (const float*)d_in[0];   // [4,2048,1024]
    const float* w_qkv = (const float*)d_in[1];   // [3072,1024]
    const float* w_out = (const float*)d_in[2];   // [1024,1024]
    const float* b_out = (const float*)d_in[3];   // [1024]
    float* out = (float*)d_out;                   // [4,2048,1024] fp32

    u16* xb    = (u16*)d_ws;                              // 8192*1024
    u16* wqkvb = xb    + (size_t)8192 * 1024;             // 3072*1024
    u16* woutb = wqkvb + (size_t)3072 * 1024;             // 1024*1024
    u16* qkb   = woutb + (size_t)1024 * 1024;             // 8192*2048 (Q|K)
    u16* vtg   = qkb   + (size_t)8192 * 2048;             // 64*64*2048 (V^T per bh)
    u16* attb  = vtg   + (size_t)64 * 64 * 2048;          // 8192*1024
    // total ws use: 92,274,688 bytes

    castk<<<8192, 256, 0, stream>>>(x, xb, 8192 * 1024, 0);
    castk<<<3072, 256, 0, stream>>>(w_qkv, wqkvb, 3072 * 1024, 1024 * 1024); // q-rows * 0.125*log2e
    castk<<<1024, 256, 0, stream>>>(w_out, woutb, 1024 * 1024, 0);

    gemm_bt<0><<<dim3((8192 / 128) * (3072 / 128)), 256, 0, stream>>>(
        xb, wqkvb, qkb, vtg, 8192, 3072, 1024);

    attn_fwd<<<1024, 256, 0, stream>>>(qkb, vtg, attb);

    gemm_bt<1><<<dim3((8192 / 128) * (1024 / 128)), 256, 0, stream>>>(
        attb, woutb, out, (void*)b_out, 8192, 1024, 1024);
}